// Round 1
// baseline (486.356 us; speedup 1.0000x reference)
//
#include <hip/hip_runtime.h>
#include <math.h>

#define BTOT 65536
#define NM   64
#define FIN  6
#define HID  64
#define FOUT 3

// d_out float32 layout (flat concat of reference tuple):
#define MO_OFF  0            // model_outputs (B,2,3) -> 393216
#define IDX_OFF 393216       // selection_indices (B) stored as float
#define LOG_OFF 458752       // selection_logits (B,64) = 1.0f
#define PRB_OFF 4653056      // selection_probabilities (B,64) = 1/64
#define OUT_END 8847360

static __device__ __forceinline__ float relu(float a) { return fmaxf(a, 0.0f); }

// ---------------- K1: selection index + histogram + idx output ----------------
__global__ void k_index(const float* __restrict__ in, float* __restrict__ out,
                        int* __restrict__ wsidx, int* __restrict__ hist)
{
    __shared__ int lh[NM];
    const int tid = threadIdx.x;
    if (tid < NM) lh[tid] = 0;
    __syncthreads();

    const int b = blockIdx.x * 256 + tid;
    const float xv = in[b * 6 + 0];
    const float zv = in[b * 6 + 2];
    const float TWO_PI = 6.28318530717958647692f;  // rounds to 6.2831855f
    // correctly-rounded f32 atan2 via double, then replicate the f32 reference ops
    float af = (float)atan2((double)zv, (double)xv);
    float t = fmodf(af + TWO_PI, TWO_PI) / TWO_PI * 64.0f;
    int idx = (int)floorf(t);
    idx = min(max(idx, 0), 63);

    wsidx[b] = idx;
    out[IDX_OFF + b] = (float)idx;

    atomicAdd(&lh[idx], 1);
    __syncthreads();
    if (tid < NM) { int c = lh[tid]; if (c) atomicAdd(&hist[tid], c); }
}

// ---------------- K2: tiny exclusive scan over 64 bins ----------------
__global__ void k_scan(const int* __restrict__ hist, int* __restrict__ off,
                       int* __restrict__ cur)
{
    if (threadIdx.x == 0) {
        int run = 0;
        for (int m = 0; m < NM; ++m) { off[m] = run; cur[m] = run; run += hist[m]; }
    }
}

// ---------------- K3: block-aggregated scatter (counting sort) ----------------
__global__ void k_scatter(const int* __restrict__ wsidx, int* __restrict__ cur,
                          int* __restrict__ sorted)
{
    __shared__ int lh[NM];
    __shared__ int lbase[NM];
    const int tid = threadIdx.x;
    if (tid < NM) lh[tid] = 0;
    __syncthreads();

    const int b = blockIdx.x * 256 + tid;
    const int idx = wsidx[b];
    const int lrank = atomicAdd(&lh[idx], 1);
    __syncthreads();

    if (tid < NM) {
        int c = lh[tid];
        lbase[tid] = c ? atomicAdd(&cur[tid], c) : 0;
    }
    __syncthreads();

    sorted[lbase[idx] + lrank] = b;
}

// ---------------- K4: per-model MLP (weights wave-uniform -> scalar loads) ----
__device__ __forceinline__ void layer64(const float* __restrict__ w,
                                        const float* __restrict__ bias,
                                        const float (&h)[HID], float (&hn)[HID])
{
#pragma unroll
    for (int o = 0; o < HID; o += 4) {
        float a0 = bias[o + 0], a1 = bias[o + 1], a2 = bias[o + 2], a3 = bias[o + 3];
#pragma unroll
        for (int i = 0; i < HID; ++i) {
            const float hi = h[i];
            a0 = fmaf(w[(o + 0) * HID + i], hi, a0);
            a1 = fmaf(w[(o + 1) * HID + i], hi, a1);
            a2 = fmaf(w[(o + 2) * HID + i], hi, a2);
            a3 = fmaf(w[(o + 3) * HID + i], hi, a3);
        }
        hn[o + 0] = relu(a0);
        hn[o + 1] = relu(a1);
        hn[o + 2] = relu(a2);
        hn[o + 3] = relu(a3);
    }
}

__device__ __forceinline__ void layerF(const float* __restrict__ w,
                                       const float* __restrict__ bias,
                                       const float (&h)[HID], float (&o3)[FOUT])
{
#pragma unroll
    for (int q = 0; q < FOUT; ++q) {
        float a = bias[q];
#pragma unroll
        for (int i = 0; i < HID; ++i) a = fmaf(w[q * HID + i], h[i], a);
        o3[q] = a;
    }
}

__global__ __launch_bounds__(256) void k_mlp(
    const float* __restrict__ in,
    const float* __restrict__ W0, const float* __restrict__ B0,
    const float* __restrict__ W1, const float* __restrict__ B1,
    const float* __restrict__ W2, const float* __restrict__ B2,
    const float* __restrict__ W3, const float* __restrict__ B3,
    const float* __restrict__ WF, const float* __restrict__ BF,
    const int* __restrict__ sorted, const int* __restrict__ off,
    const int* __restrict__ cnt, float* __restrict__ out)
{
    const int m = blockIdx.x;                 // model id, wave-uniform
    const int n = cnt[m];
    const int base = off[m];

    const float* __restrict__ w0 = W0 + m * HID * FIN;
    const float* __restrict__ b0 = B0 + m * HID;
    const float* __restrict__ w1 = W1 + m * HID * HID;
    const float* __restrict__ b1 = B1 + m * HID;
    const float* __restrict__ w2 = W2 + m * HID * HID;
    const float* __restrict__ b2 = B2 + m * HID;
    const float* __restrict__ w3 = W3 + m * HID * HID;
    const float* __restrict__ b3 = B3 + m * HID;
    const float* __restrict__ wf = WF + m * FOUT * HID;
    const float* __restrict__ bf = BF + m * FOUT;

    for (int start = blockIdx.y * 256; start < n; start += gridDim.y * 256) {
        const int s = start + (int)threadIdx.x;
        const bool act = (s < n);
        const int b = sorted[base + (act ? s : 0)];

        float x[FIN];
#pragma unroll
        for (int i = 0; i < FIN; ++i) x[i] = in[b * 6 + i];

        float h[HID], g[HID];
        // layer 0: (64x6)
#pragma unroll
        for (int o = 0; o < HID; ++o) {
            float a = b0[o];
#pragma unroll
            for (int i = 0; i < FIN; ++i) a = fmaf(w0[o * FIN + i], x[i], a);
            h[o] = relu(a);
        }
        // layer 1
        layer64(w1, b1, h, g);
        float oa[FOUT];
        layerF(wf, bf, g, oa);          // output after layer 1
        // layer 2
        layer64(w2, b2, g, h);
        // layer 3
        layer64(w3, b3, h, g);
        float ob[FOUT];
        layerF(wf, bf, g, ob);          // output after layer 3

        if (act) {
            float* p = out + MO_OFF + (size_t)b * 6;
            p[0] = oa[0]; p[1] = oa[1]; p[2] = oa[2];
            p[3] = ob[0]; p[4] = ob[1]; p[5] = ob[2];
        }
    }
}

// ---------------- K5: constant fill for logits / probabilities ----------------
__global__ void k_fill(float4* __restrict__ out4)
{
    const int start = LOG_OFF / 4;    // 114688
    const int split = PRB_OFF / 4;    // 1163264
    const int end   = OUT_END / 4;    // 2211840
    const float4 ones = make_float4(1.0f, 1.0f, 1.0f, 1.0f);
    const float4 prob = make_float4(0.015625f, 0.015625f, 0.015625f, 0.015625f);
    for (int i = start + blockIdx.x * blockDim.x + threadIdx.x; i < end;
         i += gridDim.x * blockDim.x) {
        out4[i] = (i < split) ? ones : prob;
    }
}

extern "C" void kernel_launch(void* const* d_in, const int* in_sizes, int n_in,
                              void* d_out, int out_size, void* d_ws, size_t ws_size,
                              hipStream_t stream)
{
    const float* in = (const float*)d_in[0];
    const float* W0 = (const float*)d_in[1];
    const float* B0 = (const float*)d_in[2];
    const float* W1 = (const float*)d_in[3];
    const float* B1 = (const float*)d_in[4];
    const float* W2 = (const float*)d_in[5];
    const float* B2 = (const float*)d_in[6];
    const float* W3 = (const float*)d_in[7];
    const float* B3 = (const float*)d_in[8];
    const float* WF = (const float*)d_in[9];
    const float* BF = (const float*)d_in[10];
    float* out = (float*)d_out;

    char* ws = (char*)d_ws;
    int* wsidx  = (int*)ws;                       // 65536 ints
    int* sorted = (int*)(ws + BTOT * 4);          // 65536 ints
    int* hist   = (int*)(ws + 2 * BTOT * 4);      // 64
    int* off    = hist + NM;                      // 64
    int* cur    = hist + 2 * NM;                  // 64

    hipMemsetAsync(hist, 0, NM * sizeof(int), stream);
    k_index<<<BTOT / 256, 256, 0, stream>>>(in, out, wsidx, hist);
    k_scan<<<1, 64, 0, stream>>>(hist, off, cur);
    k_scatter<<<BTOT / 256, 256, 0, stream>>>(wsidx, cur, sorted);
    k_mlp<<<dim3(NM, 8), 256, 0, stream>>>(in, W0, B0, W1, B1, W2, B2, W3, B3,
                                           WF, BF, sorted, off, hist, out);
    k_fill<<<2048, 256, 0, stream>>>((float4*)out);
}

// Round 2
// 57.057 us; speedup vs baseline: 8.5240x; 8.5240x over previous
//
#include <hip/hip_runtime.h>
#include <math.h>

#define BTOT 65536
#define NM   64
#define FIN  6
#define HID  64
#define FOUT 3

// d_out float32 layout (flat concat of reference tuple):
#define MO_OFF  0            // model_outputs (B,2,3) -> 393216
#define IDX_OFF 393216       // selection_indices (B) stored as float
#define LOG_OFF 458752       // selection_logits (B,64) = 1.0f
#define PRB_OFF 4653056      // selection_probabilities (B,64) = 1/64
#define OUT_END 8847360

typedef __attribute__((ext_vector_type(8))) short short8v;
typedef __attribute__((ext_vector_type(4))) float f32x4;

union AB { uint u[4]; uint4 q; short8v v; };

static __device__ __forceinline__ uint pack_hi2(float a, float b) {
    return (__float_as_uint(b) & 0xFFFF0000u) | (__float_as_uint(a) >> 16);
}
static __device__ __forceinline__ float hi_part(float a) {
    return __uint_as_float(__float_as_uint(a) & 0xFFFF0000u);
}
// split 8 f32 -> hi frag + lo frag (bf16 truncation; lo catches residual)
static __device__ __forceinline__ void split8(const float (&e)[8], AB& hi, AB& lo) {
#pragma unroll
    for (int t = 0; t < 4; ++t) {
        float a = e[2 * t], b = e[2 * t + 1];
        hi.u[t] = pack_hi2(a, b);
        lo.u[t] = pack_hi2(a - hi_part(a), b - hi_part(b));
    }
}
static __device__ __forceinline__ f32x4 mf(const AB& a, const AB& b, f32x4 c) {
    return __builtin_amdgcn_mfma_f32_16x16x32_bf16(a.v, b.v, c, 0, 0, 0);
}

// ---------------- K1: selection index + histogram + idx output ----------------
__global__ void k_index(const float* __restrict__ in, float* __restrict__ out,
                        int* __restrict__ wsidx, int* __restrict__ hist)
{
    __shared__ int lh[NM];
    const int tid = threadIdx.x;
    if (tid < NM) lh[tid] = 0;
    __syncthreads();

    const int b = blockIdx.x * 256 + tid;
    const float xv = in[b * 6 + 0];
    const float zv = in[b * 6 + 2];
    const float TWO_PI = 6.28318530717958647692f;
    float af = (float)atan2((double)zv, (double)xv);
    float t = fmodf(af + TWO_PI, TWO_PI) / TWO_PI * 64.0f;
    int idx = (int)floorf(t);
    idx = min(max(idx, 0), 63);

    wsidx[b] = idx;
    out[IDX_OFF + b] = (float)idx;

    atomicAdd(&lh[idx], 1);
    __syncthreads();
    if (tid < NM) { int c = lh[tid]; if (c) atomicAdd(&hist[tid], c); }
}

// ---------------- K2: tiny exclusive scan over 64 bins ----------------
__global__ void k_scan(const int* __restrict__ hist, int* __restrict__ off,
                       int* __restrict__ cur)
{
    if (threadIdx.x == 0) {
        int run = 0;
        for (int m = 0; m < NM; ++m) { off[m] = run; cur[m] = run; run += hist[m]; }
    }
}

// ---------------- K3: block-aggregated scatter (counting sort) ----------------
__global__ void k_scatter(const int* __restrict__ wsidx, int* __restrict__ cur,
                          int* __restrict__ sorted)
{
    __shared__ int lh[NM];
    __shared__ int lbase[NM];
    const int tid = threadIdx.x;
    if (tid < NM) lh[tid] = 0;
    __syncthreads();

    const int b = blockIdx.x * 256 + tid;
    const int idx = wsidx[b];
    const int lrank = atomicAdd(&lh[idx], 1);
    __syncthreads();

    if (tid < NM) {
        int c = lh[tid];
        lbase[tid] = c ? atomicAdd(&cur[tid], c) : 0;
    }
    __syncthreads();

    sorted[lbase[idx] + lrank] = b;
}

// ---------------- K4: MFMA MLP ----------------
// Sets: 0..3 = L0 (kstep 0, ntile 0..3); 4..27 = L1..L3 (8 each: ks*4+nt);
// 28..29 = LF (kstep 0..1, ntile 0).
#define NSETS 30
#define HSTRIDE 68

__global__ __launch_bounds__(512, 1) void k_mlp(
    const float* __restrict__ in,
    const float* __restrict__ W0, const float* __restrict__ B0,
    const float* __restrict__ W1, const float* __restrict__ B1,
    const float* __restrict__ W2, const float* __restrict__ B2,
    const float* __restrict__ W3, const float* __restrict__ B3,
    const float* __restrict__ WF, const float* __restrict__ BF,
    const int* __restrict__ sorted, const int* __restrict__ offs,
    const int* __restrict__ cnt, float* __restrict__ out)
{
    __shared__ uint bhS[NSETS][64][4];          // 30720 B  (hi plane)
    __shared__ uint blS[NSETS][64][4];          // 30720 B  (lo plane)
    __shared__ float hsS[8][32 * HSTRIDE];      // 69632 B  (per-wave H scratch)

    const int m = blockIdx.x;
    const int tid = threadIdx.x;
    const int wid = tid >> 6;
    const int lane = tid & 63;
    const int g = lane >> 4;      // k-group / row-group
    const int c16 = lane & 15;    // column within tile

    // ---- prologue: convert+swizzle weights into B-fragment planes ----
    for (int job = tid; job < NSETS * 64; job += 512) {
        const int set = job >> 6, ln = job & 63;
        const int gq = ln >> 4, cq = ln & 15;
        float e[8];
        if (set < 4) {                                   // L0: K=6 padded to 32
            const int col = set * 16 + cq;
            const float* w = W0 + m * (HID * FIN) + col * FIN;
            const int kb = gq * 8;
#pragma unroll
            for (int j = 0; j < 8; ++j) { int k = kb + j; e[j] = (k < FIN) ? w[k] : 0.0f; }
        } else if (set < 28) {                           // L1..L3
            const int q = set - 4;
            const int ly = q >> 3, ks = (q & 7) >> 2, nt = q & 3;
            const int col = nt * 16 + cq;
            const float* Wl = (ly == 0) ? W1 : (ly == 1) ? W2 : W3;
            const float4* w4 = (const float4*)(Wl + m * (HID * HID) + col * HID + ks * 32 + gq * 8);
            float4 f0 = w4[0], f1 = w4[1];
            e[0] = f0.x; e[1] = f0.y; e[2] = f0.z; e[3] = f0.w;
            e[4] = f1.x; e[5] = f1.y; e[6] = f1.z; e[7] = f1.w;
        } else {                                         // LF: 3 valid cols
            const int ks = set - 28;
            if (cq < FOUT) {
                const float* w = WF + m * (FOUT * HID) + cq * HID + ks * 32 + gq * 8;
#pragma unroll
                for (int j = 0; j < 8; ++j) e[j] = w[j];
            } else {
#pragma unroll
                for (int j = 0; j < 8; ++j) e[j] = 0.0f;
            }
        }
        AB hi, lo;
        split8(e, hi, lo);
        *(uint4*)&bhS[set][ln][0] = hi.q;
        *(uint4*)&blS[set][ln][0] = lo.q;
    }

    // per-lane bias registers
    float b0v[4], b1v[4], b2v[4], b3v[4];
#pragma unroll
    for (int t = 0; t < 4; ++t) {
        const int c = t * 16 + c16;
        b0v[t] = B0[m * HID + c];
        b1v[t] = B1[m * HID + c];
        b2v[t] = B2[m * HID + c];
        b3v[t] = B3[m * HID + c];
    }
    const float bfv = (c16 < FOUT) ? BF[m * FOUT + c16] : 0.0f;

    const int n = cnt[m];
    const int base = offs[m];

    __syncthreads();

    float* __restrict__ hw = hsS[wid];

    for (int ti = blockIdx.y * 8 + wid; ti * 32 < n; ti += 32) {
        f32x4 acc[2][4];
        AB ah[2][2], al[2][2];

        // ---- L0 ----
#pragma unroll
        for (int mt = 0; mt < 2; ++mt) {
            AB a0h, a0l;
            if (g == 0) {
                int s = ti * 32 + mt * 16 + c16; if (s >= n) s = n - 1;
                const int b = sorted[base + s];
                const float* xp = in + b * 6;
                float e[8];
#pragma unroll
                for (int j = 0; j < 8; ++j) e[j] = (j < FIN) ? xp[j] : 0.0f;
                split8(e, a0h, a0l);
            } else {
#pragma unroll
                for (int t = 0; t < 4; ++t) { a0h.u[t] = 0u; a0l.u[t] = 0u; }
            }
#pragma unroll
            for (int t = 0; t < 4; ++t) {
                AB bh, bl;
                bh.q = *(const uint4*)&bhS[t][lane][0];
                bl.q = *(const uint4*)&blS[t][lane][0];
                f32x4 c = {b0v[t], b0v[t], b0v[t], b0v[t]};
                c = mf(a0h, bh, c); c = mf(a0h, bl, c); c = mf(a0l, bh, c);
                acc[mt][t] = c;
            }
        }

        // store_relu + readA macro-ish helpers (manual, fully unrolled)
#define STORE_RELU()                                                          \
        _Pragma("unroll")                                                     \
        for (int mt = 0; mt < 2; ++mt)                                        \
        _Pragma("unroll")                                                     \
        for (int t = 0; t < 4; ++t)                                           \
        _Pragma("unroll")                                                     \
        for (int r = 0; r < 4; ++r) {                                         \
            float v = fmaxf(acc[mt][t][r], 0.0f);                             \
            const int row = mt * 16 + g * 4 + r;                              \
            const int col = (t * 16 + c16) ^ (r << 3);                        \
            hw[row * HSTRIDE + col] = v;                                      \
        }

#define READ_A()                                                              \
        _Pragma("unroll")                                                     \
        for (int mt = 0; mt < 2; ++mt) {                                      \
            const int row = mt * 16 + c16;                                    \
            const int rb = row * HSTRIDE;                                     \
            const int rs = row & 3;                                           \
            _Pragma("unroll")                                                 \
            for (int ks = 0; ks < 2; ++ks) {                                  \
                const int cgs = (ks * 4 + g) ^ rs;                            \
                const float* p = hw + rb + cgs * 8;                           \
                float4 f0 = *(const float4*)p;                                \
                float4 f1 = *(const float4*)(p + 4);                          \
                float e[8] = {f0.x, f0.y, f0.z, f0.w, f1.x, f1.y, f1.z, f1.w};\
                split8(e, ah[mt][ks], al[mt][ks]);                            \
            }                                                                 \
        }

#define LAYER64(SET0, BV)                                                     \
        _Pragma("unroll")                                                     \
        for (int ks = 0; ks < 2; ++ks)                                        \
        _Pragma("unroll")                                                     \
        for (int t = 0; t < 4; ++t) {                                         \
            AB bh, bl;                                                        \
            bh.q = *(const uint4*)&bhS[(SET0) + ks * 4 + t][lane][0];         \
            bl.q = *(const uint4*)&blS[(SET0) + ks * 4 + t][lane][0];         \
            _Pragma("unroll")                                                 \
            for (int mt = 0; mt < 2; ++mt) {                                  \
                f32x4 c = (ks == 0) ? f32x4{BV[t], BV[t], BV[t], BV[t]}       \
                                    : acc[mt][t];                             \
                c = mf(ah[mt][ks], bh, c);                                    \
                c = mf(ah[mt][ks], bl, c);                                    \
                c = mf(al[mt][ks], bh, c);                                    \
                acc[mt][t] = c;                                               \
            }                                                                 \
        }

#define LFINAL(PASS)                                                          \
        _Pragma("unroll")                                                     \
        for (int mt = 0; mt < 2; ++mt) {                                      \
            f32x4 o = {bfv, bfv, bfv, bfv};                                   \
            _Pragma("unroll")                                                 \
            for (int ks = 0; ks < 2; ++ks) {                                  \
                AB bh, bl;                                                    \
                bh.q = *(const uint4*)&bhS[28 + ks][lane][0];                 \
                bl.q = *(const uint4*)&blS[28 + ks][lane][0];                 \
                o = mf(ah[mt][ks], bh, o);                                    \
                o = mf(ah[mt][ks], bl, o);                                    \
                o = mf(al[mt][ks], bh, o);                                    \
            }                                                                 \
            _Pragma("unroll")                                                 \
            for (int r = 0; r < 4; ++r) {                                     \
                const int s = ti * 32 + mt * 16 + g * 4 + r;                  \
                if (c16 < FOUT && s < n) {                                    \
                    const int b = sorted[base + s];                           \
                    out[MO_OFF + b * 6 + (PASS) * 3 + c16] = o[r];            \
                }                                                             \
            }                                                                 \
        }

        STORE_RELU();     // H0
        READ_A();         // A = H0
        LAYER64(4, b1v);  // L1
        STORE_RELU();     // H1
        READ_A();         // A = H1
        LFINAL(0);        // output after layer 1
        LAYER64(12, b2v); // L2
        STORE_RELU();     // H2
        READ_A();         // A = H2
        LAYER64(20, b3v); // L3
        STORE_RELU();     // H3
        READ_A();         // A = H3
        LFINAL(1);        // final output
    }
}

// ---------------- K5: constant fill for logits / probabilities ----------------
__global__ void k_fill(float4* __restrict__ out4)
{
    const int start = LOG_OFF / 4;
    const int split = PRB_OFF / 4;
    const int end   = OUT_END / 4;
    const float4 ones = make_float4(1.0f, 1.0f, 1.0f, 1.0f);
    const float4 prob = make_float4(0.015625f, 0.015625f, 0.015625f, 0.015625f);
    for (int i = start + blockIdx.x * blockDim.x + threadIdx.x; i < end;
         i += gridDim.x * blockDim.x) {
        out4[i] = (i < split) ? ones : prob;
    }
}

extern "C" void kernel_launch(void* const* d_in, const int* in_sizes, int n_in,
                              void* d_out, int out_size, void* d_ws, size_t ws_size,
                              hipStream_t stream)
{
    const float* in = (const float*)d_in[0];
    const float* W0 = (const float*)d_in[1];
    const float* B0 = (const float*)d_in[2];
    const float* W1 = (const float*)d_in[3];
    const float* B1 = (const float*)d_in[4];
    const float* W2 = (const float*)d_in[5];
    const float* B2 = (const float*)d_in[6];
    const float* W3 = (const float*)d_in[7];
    const float* B3 = (const float*)d_in[8];
    const float* WF = (const float*)d_in[9];
    const float* BF = (const float*)d_in[10];
    float* out = (float*)d_out;

    char* ws = (char*)d_ws;
    int* wsidx  = (int*)ws;                       // 65536 ints
    int* sorted = (int*)(ws + BTOT * 4);          // 65536 ints
    int* hist   = (int*)(ws + 2 * BTOT * 4);      // 64
    int* off    = hist + NM;                      // 64
    int* cur    = hist + 2 * NM;                  // 64

    hipMemsetAsync(hist, 0, NM * sizeof(int), stream);
    k_index<<<BTOT / 256, 256, 0, stream>>>(in, out, wsidx, hist);
    k_scan<<<1, 64, 0, stream>>>(hist, off, cur);
    k_scatter<<<BTOT / 256, 256, 0, stream>>>(wsidx, cur, sorted);
    k_mlp<<<dim3(NM, 4), 512, 0, stream>>>(in, W0, B0, W1, B1, W2, B2, W3, B3,
                                           WF, BF, sorted, off, hist, out);
    k_fill<<<2048, 256, 0, stream>>>((float4*)out);
}

// Round 3
// 52.974 us; speedup vs baseline: 9.1811x; 1.0771x over previous
//
#include <hip/hip_runtime.h>
#include <math.h>

#define BTOT 65536
#define NM   64
#define FIN  6
#define HID  64
#define FOUT 3

// d_out float32 layout (flat concat of reference tuple):
#define MO_OFF  0            // model_outputs (B,2,3) -> 393216
#define IDX_OFF 393216       // selection_indices (B) stored as float
#define LOG_OFF 458752       // selection_logits (B,64) = 1.0f
#define PRB_OFF 4653056      // selection_probabilities (B,64) = 1/64
#define OUT_END 8847360

typedef __attribute__((ext_vector_type(8))) short short8v;
typedef __attribute__((ext_vector_type(4))) float f32x4;

union AB { uint u[4]; uint4 q; short8v v; };

static __device__ __forceinline__ uint pack_hi2(float a, float b) {
    return (__float_as_uint(b) & 0xFFFF0000u) | (__float_as_uint(a) >> 16);
}
static __device__ __forceinline__ float hi_part(float a) {
    return __uint_as_float(__float_as_uint(a) & 0xFFFF0000u);
}
// split 8 f32 -> hi frag + lo frag (bf16 truncation; lo catches residual)
static __device__ __forceinline__ void split8(const float (&e)[8], AB& hi, AB& lo) {
#pragma unroll
    for (int t = 0; t < 4; ++t) {
        float a = e[2 * t], b = e[2 * t + 1];
        hi.u[t] = pack_hi2(a, b);
        lo.u[t] = pack_hi2(a - hi_part(a), b - hi_part(b));
    }
}
static __device__ __forceinline__ f32x4 mf(const AB& a, const AB& b, f32x4 c) {
    return __builtin_amdgcn_mfma_f32_16x16x32_bf16(a.v, b.v, c, 0, 0, 0);
}

// ---------------- K0: zero hist+cur (replaces pathological hipMemsetAsync) ----
__global__ void k_zero(int* __restrict__ p)
{
    p[threadIdx.x] = 0;   // 128 threads: hist[64] + cur[64]
}

// ------------- K1: selection index + histogram + idx output + const fill ------
__global__ void k_index_fill(const float* __restrict__ in, float* __restrict__ out,
                             int* __restrict__ wsidx, int* __restrict__ hist)
{
    __shared__ int lh[NM];
    const int tid = threadIdx.x;
    const int bid = blockIdx.x;

    if (bid < 256) {
        if (tid < NM) lh[tid] = 0;
        __syncthreads();

        const int b = bid * 256 + tid;
        const float xv = in[b * 6 + 0];
        const float zv = in[b * 6 + 2];
        const float TWO_PI = 6.28318530717958647692f;
        float af = (float)atan2((double)zv, (double)xv);
        float t = fmodf(af + TWO_PI, TWO_PI) / TWO_PI * 64.0f;
        int idx = (int)floorf(t);
        idx = min(max(idx, 0), 63);

        wsidx[b] = idx;
        out[IDX_OFF + b] = (float)idx;

        atomicAdd(&lh[idx], 1);
        __syncthreads();
        if (tid < NM) { int c = lh[tid]; if (c) atomicAdd(&hist[tid], c); }
    }

    // constant fill of logits / probabilities (grid-stride over all 2048 blocks)
    float4* __restrict__ out4 = (float4*)out;
    const int start = LOG_OFF / 4;
    const int split = PRB_OFF / 4;
    const int end   = OUT_END / 4;
    const float4 ones = make_float4(1.0f, 1.0f, 1.0f, 1.0f);
    const float4 prob = make_float4(0.015625f, 0.015625f, 0.015625f, 0.015625f);
    for (int i = start + bid * 256 + tid; i < end; i += 2048 * 256) {
        out4[i] = (i < split) ? ones : prob;
    }
}

// -------- K2: block-aggregated scatter (counting sort, local 64-bin prefix) ---
__global__ void k_scatter(const int* __restrict__ wsidx, const int* __restrict__ hist,
                          int* __restrict__ cur, int* __restrict__ sorted)
{
    __shared__ int lh[NM];
    __shared__ int lbase[NM];
    __shared__ int shist[NM];
    const int tid = threadIdx.x;
    if (tid < NM) { lh[tid] = 0; shist[tid] = hist[tid]; }
    __syncthreads();

    const int b = blockIdx.x * 256 + tid;
    const int idx = wsidx[b];
    const int lrank = atomicAdd(&lh[idx], 1);
    __syncthreads();

    if (tid < NM) {
        int off = 0;
#pragma unroll 8
        for (int m = 0; m < NM; ++m) off += (m < tid) ? shist[m] : 0;
        int c = lh[tid];
        lbase[tid] = off + (c ? atomicAdd(&cur[tid], c) : 0);
    }
    __syncthreads();

    sorted[lbase[idx] + lrank] = b;
}

// ---------------- K3: MFMA MLP ----------------
// Sets: 0..3 = L0 (kstep 0, ntile 0..3); 4..27 = L1..L3 (8 each: ks*4+nt);
// 28..29 = LF (kstep 0..1, ntile 0).
#define NSETS 30
#define HSTRIDE 68

__global__ __launch_bounds__(512, 1) void k_mlp(
    const float* __restrict__ in,
    const float* __restrict__ W0, const float* __restrict__ B0,
    const float* __restrict__ W1, const float* __restrict__ B1,
    const float* __restrict__ W2, const float* __restrict__ B2,
    const float* __restrict__ W3, const float* __restrict__ B3,
    const float* __restrict__ WF, const float* __restrict__ BF,
    const int* __restrict__ sorted, const int* __restrict__ cnt,
    float* __restrict__ out)
{
    __shared__ uint bhS[NSETS][64][4];          // 30720 B  (hi plane)
    __shared__ uint blS[NSETS][64][4];          // 30720 B  (lo plane)
    __shared__ float hsS[8][32 * HSTRIDE];      // 69632 B  (per-wave H scratch)
    __shared__ int shist[NM];
    __shared__ int sbase;

    const int m = blockIdx.x;
    const int tid = threadIdx.x;
    const int wid = tid >> 6;
    const int lane = tid & 63;
    const int g = lane >> 4;      // k-group / row-group
    const int c16 = lane & 15;    // column within tile

    if (tid < NM) shist[tid] = cnt[tid];
    __syncthreads();
    const int n = shist[m];
    if (tid == 0) {
        int run = 0;
        for (int i = 0; i < NM; ++i) run += (i < m) ? shist[i] : 0;
        sbase = run;
    }

    // ---- prologue: convert+swizzle weights into B-fragment planes ----
    for (int job = tid; job < NSETS * 64; job += 512) {
        const int set = job >> 6, ln = job & 63;
        const int gq = ln >> 4, cq = ln & 15;
        float e[8];
        if (set < 4) {                                   // L0: K=6 padded to 32
            const int col = set * 16 + cq;
            const float* w = W0 + m * (HID * FIN) + col * FIN;
            const int kb = gq * 8;
#pragma unroll
            for (int j = 0; j < 8; ++j) { int k = kb + j; e[j] = (k < FIN) ? w[k] : 0.0f; }
        } else if (set < 28) {                           // L1..L3
            const int q = set - 4;
            const int ly = q >> 3, ks = (q & 7) >> 2, nt = q & 3;
            const int col = nt * 16 + cq;
            const float* Wl = (ly == 0) ? W1 : (ly == 1) ? W2 : W3;
            const float4* w4 = (const float4*)(Wl + m * (HID * HID) + col * HID + ks * 32 + gq * 8);
            float4 f0 = w4[0], f1 = w4[1];
            e[0] = f0.x; e[1] = f0.y; e[2] = f0.z; e[3] = f0.w;
            e[4] = f1.x; e[5] = f1.y; e[6] = f1.z; e[7] = f1.w;
        } else {                                         // LF: 3 valid cols
            const int ks = set - 28;
            if (cq < FOUT) {
                const float* w = WF + m * (FOUT * HID) + cq * HID + ks * 32 + gq * 8;
#pragma unroll
                for (int j = 0; j < 8; ++j) e[j] = w[j];
            } else {
#pragma unroll
                for (int j = 0; j < 8; ++j) e[j] = 0.0f;
            }
        }
        AB hi, lo;
        split8(e, hi, lo);
        *(uint4*)&bhS[set][ln][0] = hi.q;
        *(uint4*)&blS[set][ln][0] = lo.q;
    }

    // per-lane bias registers
    float b0v[4], b1v[4], b2v[4], b3v[4];
#pragma unroll
    for (int t = 0; t < 4; ++t) {
        const int c = t * 16 + c16;
        b0v[t] = B0[m * HID + c];
        b1v[t] = B1[m * HID + c];
        b2v[t] = B2[m * HID + c];
        b3v[t] = B3[m * HID + c];
    }
    const float bfv = (c16 < FOUT) ? BF[m * FOUT + c16] : 0.0f;

    __syncthreads();
    const int base = sbase;

    float* __restrict__ hw = hsS[wid];

    for (int ti = blockIdx.y * 8 + wid; ti * 32 < n; ti += 32) {
        f32x4 acc[2][4];
        AB ah[2][2], al[2][2];

        // ---- L0 ----
#pragma unroll
        for (int mt = 0; mt < 2; ++mt) {
            AB a0h, a0l;
            if (g == 0) {
                int s = ti * 32 + mt * 16 + c16; if (s >= n) s = n - 1;
                const int b = sorted[base + s];
                const float* xp = in + b * 6;
                float e[8];
#pragma unroll
                for (int j = 0; j < 8; ++j) e[j] = (j < FIN) ? xp[j] : 0.0f;
                split8(e, a0h, a0l);
            } else {
#pragma unroll
                for (int t = 0; t < 4; ++t) { a0h.u[t] = 0u; a0l.u[t] = 0u; }
            }
#pragma unroll
            for (int t = 0; t < 4; ++t) {
                AB bh, bl;
                bh.q = *(const uint4*)&bhS[t][lane][0];
                bl.q = *(const uint4*)&blS[t][lane][0];
                f32x4 c = {b0v[t], b0v[t], b0v[t], b0v[t]};
                c = mf(a0h, bh, c); c = mf(a0h, bl, c); c = mf(a0l, bh, c);
                acc[mt][t] = c;
            }
        }

#define STORE_RELU()                                                          \
        _Pragma("unroll")                                                     \
        for (int mt = 0; mt < 2; ++mt)                                        \
        _Pragma("unroll")                                                     \
        for (int t = 0; t < 4; ++t)                                           \
        _Pragma("unroll")                                                     \
        for (int r = 0; r < 4; ++r) {                                         \
            float v = fmaxf(acc[mt][t][r], 0.0f);                             \
            const int row = mt * 16 + g * 4 + r;                              \
            const int col = (t * 16 + c16) ^ (r << 3);                        \
            hw[row * HSTRIDE + col] = v;                                      \
        }

#define READ_A()                                                              \
        _Pragma("unroll")                                                     \
        for (int mt = 0; mt < 2; ++mt) {                                      \
            const int row = mt * 16 + c16;                                    \
            const int rb = row * HSTRIDE;                                     \
            const int rs = row & 3;                                           \
            _Pragma("unroll")                                                 \
            for (int ks = 0; ks < 2; ++ks) {                                  \
                const int cgs = (ks * 4 + g) ^ rs;                            \
                const float* p = hw + rb + cgs * 8;                           \
                float4 f0 = *(const float4*)p;                                \
                float4 f1 = *(const float4*)(p + 4);                          \
                float e[8] = {f0.x, f0.y, f0.z, f0.w, f1.x, f1.y, f1.z, f1.w};\
                split8(e, ah[mt][ks], al[mt][ks]);                            \
            }                                                                 \
        }

#define LAYER64(SET0, BV)                                                     \
        _Pragma("unroll")                                                     \
        for (int ks = 0; ks < 2; ++ks)                                        \
        _Pragma("unroll")                                                     \
        for (int t = 0; t < 4; ++t) {                                         \
            AB bh, bl;                                                        \
            bh.q = *(const uint4*)&bhS[(SET0) + ks * 4 + t][lane][0];         \
            bl.q = *(const uint4*)&blS[(SET0) + ks * 4 + t][lane][0];         \
            _Pragma("unroll")                                                 \
            for (int mt = 0; mt < 2; ++mt) {                                  \
                f32x4 c = (ks == 0) ? f32x4{BV[t], BV[t], BV[t], BV[t]}       \
                                    : acc[mt][t];                             \
                c = mf(ah[mt][ks], bh, c);                                    \
                c = mf(ah[mt][ks], bl, c);                                    \
                c = mf(al[mt][ks], bh, c);                                    \
                acc[mt][t] = c;                                               \
            }                                                                 \
        }

#define LFINAL(PASS)                                                          \
        _Pragma("unroll")                                                     \
        for (int mt = 0; mt < 2; ++mt) {                                      \
            f32x4 o = {bfv, bfv, bfv, bfv};                                   \
            _Pragma("unroll")                                                 \
            for (int ks = 0; ks < 2; ++ks) {                                  \
                AB bh, bl;                                                    \
                bh.q = *(const uint4*)&bhS[28 + ks][lane][0];                 \
                bl.q = *(const uint4*)&blS[28 + ks][lane][0];                 \
                o = mf(ah[mt][ks], bh, o);                                    \
                o = mf(ah[mt][ks], bl, o);                                    \
                o = mf(al[mt][ks], bh, o);                                    \
            }                                                                 \
            _Pragma("unroll")                                                 \
            for (int r = 0; r < 4; ++r) {                                     \
                const int s = ti * 32 + mt * 16 + g * 4 + r;                  \
                if (c16 < FOUT && s < n) {                                    \
                    const int b = sorted[base + s];                           \
                    out[MO_OFF + b * 6 + (PASS) * 3 + c16] = o[r];            \
                }                                                             \
            }                                                                 \
        }

        STORE_RELU();     // H0
        READ_A();         // A = H0
        LAYER64(4, b1v);  // L1
        STORE_RELU();     // H1
        READ_A();         // A = H1
        LFINAL(0);        // output after layer 1
        LAYER64(12, b2v); // L2
        STORE_RELU();     // H2
        READ_A();         // A = H2
        LAYER64(20, b3v); // L3
        STORE_RELU();     // H3
        READ_A();         // A = H3
        LFINAL(1);        // final output
    }
}

extern "C" void kernel_launch(void* const* d_in, const int* in_sizes, int n_in,
                              void* d_out, int out_size, void* d_ws, size_t ws_size,
                              hipStream_t stream)
{
    const float* in = (const float*)d_in[0];
    const float* W0 = (const float*)d_in[1];
    const float* B0 = (const float*)d_in[2];
    const float* W1 = (const float*)d_in[3];
    const float* B1 = (const float*)d_in[4];
    const float* W2 = (const float*)d_in[5];
    const float* B2 = (const float*)d_in[6];
    const float* W3 = (const float*)d_in[7];
    const float* B3 = (const float*)d_in[8];
    const float* WF = (const float*)d_in[9];
    const float* BF = (const float*)d_in[10];
    float* out = (float*)d_out;

    char* ws = (char*)d_ws;
    int* wsidx  = (int*)ws;                       // 65536 ints
    int* sorted = (int*)(ws + BTOT * 4);          // 65536 ints
    int* hist   = (int*)(ws + 2 * BTOT * 4);      // 64
    int* cur    = hist + NM;                      // 64

    k_zero<<<1, 128, 0, stream>>>(hist);
    k_index_fill<<<2048, 256, 0, stream>>>(in, out, wsidx, hist);
    k_scatter<<<BTOT / 256, 256, 0, stream>>>(wsidx, hist, cur, sorted);
    k_mlp<<<dim3(NM, 4), 512, 0, stream>>>(in, W0, B0, W1, B1, W2, B2, W3, B3,
                                           WF, BF, sorted, hist, out);
}

// Round 4
// 43.291 us; speedup vs baseline: 11.2345x; 1.2237x over previous
//
#include <hip/hip_runtime.h>
#include <math.h>

#define BTOT 65536
#define NM   64
#define FIN  6
#define HID  64
#define FOUT 3

// d_out float32 layout (flat concat of reference tuple):
#define MO_OFF  0            // model_outputs (B,2,3) -> 393216
#define IDX_OFF 393216       // selection_indices (B) stored as float
#define LOG_OFF 458752       // selection_logits (B,64) = 1.0f
#define PRB_OFF 4653056      // selection_probabilities (B,64) = 1/64
#define OUT_END 8847360

typedef __attribute__((ext_vector_type(8))) short short8v;
typedef __attribute__((ext_vector_type(4))) float f32x4;

union AB { uint u[4]; uint4 q; short8v v; };

static __device__ __forceinline__ uint pack_hi2(float a, float b) {
    return (__float_as_uint(b) & 0xFFFF0000u) | (__float_as_uint(a) >> 16);
}
static __device__ __forceinline__ float hi_part(float a) {
    return __uint_as_float(__float_as_uint(a) & 0xFFFF0000u);
}
// split 8 f32 -> hi frag + lo frag (bf16 truncation; lo catches residual)
static __device__ __forceinline__ void split8(const float (&e)[8], AB& hi, AB& lo) {
#pragma unroll
    for (int t = 0; t < 4; ++t) {
        float a = e[2 * t], b = e[2 * t + 1];
        hi.u[t] = pack_hi2(a, b);
        lo.u[t] = pack_hi2(a - hi_part(a), b - hi_part(b));
    }
}
static __device__ __forceinline__ f32x4 mf(const AB& a, const AB& b, f32x4 c) {
    return __builtin_amdgcn_mfma_f32_16x16x32_bf16(a.v, b.v, c, 0, 0, 0);
}

// ---------------- K1: selection index -> idx output + byte map ----------------
__global__ void k_index(const float* __restrict__ in, float* __restrict__ out,
                        unsigned char* __restrict__ wsb)
{
    const int b = blockIdx.x * 256 + threadIdx.x;
    const float xv = in[b * 6 + 0];
    const float zv = in[b * 6 + 2];
    const float TWO_PI = 6.28318530717958647692f;
    float af = (float)atan2((double)zv, (double)xv);
    float t = fmodf(af + TWO_PI, TWO_PI) / TWO_PI * 64.0f;
    int idx = (int)floorf(t);
    idx = min(max(idx, 0), 63);

    wsb[b] = (unsigned char)idx;
    out[IDX_OFF + b] = (float)idx;
}

// ---------------- K2: fused MFMA MLP (self-gather + const fill) ----------------
// B-frag sets: 0..3 = L0 (ntile 0..3); 4..27 = L1..L3 (8 each: ks*4+nt);
// 28..29 = LF (kstep 0..1).
#define NSETS 30
#define HSTRIDE 68
#define LCAP 2048

__global__ __launch_bounds__(512, 1) void k_mlp(
    const float* __restrict__ in,
    const float* __restrict__ W0, const float* __restrict__ B0,
    const float* __restrict__ W1, const float* __restrict__ B1,
    const float* __restrict__ W2, const float* __restrict__ B2,
    const float* __restrict__ W3, const float* __restrict__ B3,
    const float* __restrict__ WF, const float* __restrict__ BF,
    const uint4* __restrict__ wsb4, float* __restrict__ out)
{
    __shared__ uint bhS[NSETS][64][4];          // 30720 B  (hi plane)
    __shared__ uint blS[NSETS][64][4];          // 30720 B  (lo plane)
    __shared__ float hsS[8][32 * HSTRIDE];      // 69632 B  (per-wave H scratch)
    __shared__ int list[LCAP];                  // 8192 B   (this model's samples)
    __shared__ int wtot[8];
    __shared__ int wbase[8];
    __shared__ int s_n;

    const int m = blockIdx.x;
    const int tid = (int)threadIdx.x;
    const int wid = tid >> 6;
    const int lane = tid & 63;
    const int g = lane >> 4;      // k-group / row-group
    const int c16 = lane & 15;    // column within tile

    // ---- prologue A: convert+swizzle weights into B-fragment planes ----
    for (int job = tid; job < NSETS * 64; job += 512) {
        const int set = job >> 6, ln = job & 63;
        const int gq = ln >> 4, cq = ln & 15;
        float e[8];
        if (set < 4) {                                   // L0: K=6 padded to 32
            const int col = set * 16 + cq;
            const float* w = W0 + m * (HID * FIN) + col * FIN;
            const int kb = gq * 8;
#pragma unroll
            for (int j = 0; j < 8; ++j) { int k = kb + j; e[j] = (k < FIN) ? w[k] : 0.0f; }
        } else if (set < 28) {                           // L1..L3
            const int q = set - 4;
            const int ly = q >> 3, ks = (q & 7) >> 2, nt = q & 3;
            const int col = nt * 16 + cq;
            const float* Wl = (ly == 0) ? W1 : (ly == 1) ? W2 : W3;
            const float4* w4 = (const float4*)(Wl + m * (HID * HID) + col * HID + ks * 32 + gq * 8);
            float4 f0 = w4[0], f1 = w4[1];
            e[0] = f0.x; e[1] = f0.y; e[2] = f0.z; e[3] = f0.w;
            e[4] = f1.x; e[5] = f1.y; e[6] = f1.z; e[7] = f1.w;
        } else {                                         // LF: 3 valid cols
            const int ks = set - 28;
            if (cq < FOUT) {
                const float* w = WF + m * (FOUT * HID) + cq * HID + ks * 32 + gq * 8;
#pragma unroll
                for (int j = 0; j < 8; ++j) e[j] = w[j];
            } else {
#pragma unroll
                for (int j = 0; j < 8; ++j) e[j] = 0.0f;
            }
        }
        AB hi, lo;
        split8(e, hi, lo);
        *(uint4*)&bhS[set][ln][0] = hi.q;
        *(uint4*)&blS[set][ln][0] = lo.q;
    }

    // ---- prologue B: constant fill (stores drain under the compute below) ----
    {
        float4* __restrict__ out4 = (float4*)out;
        const int start = LOG_OFF / 4;                    // 114688
        const int split = PRB_OFF / 4;                    // 1163264
        const int blk = (int)blockIdx.y * NM + m;         // 0..255
        const float4 ones = make_float4(1.0f, 1.0f, 1.0f, 1.0f);
        const float4 prob = make_float4(0.015625f, 0.015625f, 0.015625f, 0.015625f);
        const int i0 = start + blk * 8192 + tid;
#pragma unroll
        for (int k = 0; k < 16; ++k) {
            const int i = i0 + k * 512;
            out4[i] = (i < split) ? ones : prob;          // 256 blk * 8192 = whole region
        }
    }

    // per-lane bias registers
    float b0v[4], b1v[4], b2v[4], b3v[4];
#pragma unroll
    for (int t = 0; t < 4; ++t) {
        const int c = t * 16 + c16;
        b0v[t] = B0[m * HID + c];
        b1v[t] = B1[m * HID + c];
        b2v[t] = B2[m * HID + c];
        b3v[t] = B3[m * HID + c];
    }
    const float bfv = (c16 < FOUT) ? BF[m * FOUT + c16] : 0.0f;

    // ---- prologue C: self-gather sample list (scan 64KB byte map) ----
    uint4 v[8];
    int c = 0;
#pragma unroll
    for (int j = 0; j < 8; ++j) {
        v[j] = wsb4[j * 512 + tid];
#pragma unroll
        for (int t = 0; t < 16; ++t) {
            const int bi = (int)((((const uint*)&v[j])[t >> 2] >> ((t & 3) * 8)) & 0xffu);
            c += (bi == m);
        }
    }
    // wave inclusive scan of c
    int isc = c;
#pragma unroll
    for (int d = 1; d < 64; d <<= 1) {
        int y = __shfl_up(isc, d);
        if (lane >= d) isc += y;
    }
    if (lane == 63) wtot[wid] = isc;
    __syncthreads();
    if (tid == 0) {
        int run = 0;
#pragma unroll
        for (int w = 0; w < 8; ++w) { wbase[w] = run; run += wtot[w]; }
        s_n = run;
    }
    __syncthreads();
    int pos = wbase[wid] + (isc - c);
#pragma unroll
    for (int j = 0; j < 8; ++j) {
#pragma unroll
        for (int t = 0; t < 16; ++t) {
            const int bi = (int)((((const uint*)&v[j])[t >> 2] >> ((t & 3) * 8)) & 0xffu);
            if (bi == m) {
                if (pos < LCAP) list[pos] = (j * 512 + tid) * 16 + t;
                ++pos;
            }
        }
    }
    __syncthreads();
    const int n = min(s_n, LCAP);

    float* __restrict__ hw = hsS[wid];

    for (int ti = (int)blockIdx.y * 8 + wid; ti * 32 < n; ti += 32) {
        f32x4 acc[2][4];
        AB ah[2][2], al[2][2];

        // ---- L0 ----
#pragma unroll
        for (int mt = 0; mt < 2; ++mt) {
            AB a0h, a0l;
            if (g == 0) {
                int s = ti * 32 + mt * 16 + c16; if (s >= n) s = n - 1;
                const int b = list[s];
                const float* xp = in + b * 6;
                float e[8];
#pragma unroll
                for (int j = 0; j < 8; ++j) e[j] = (j < FIN) ? xp[j] : 0.0f;
                split8(e, a0h, a0l);
            } else {
#pragma unroll
                for (int t = 0; t < 4; ++t) { a0h.u[t] = 0u; a0l.u[t] = 0u; }
            }
#pragma unroll
            for (int t = 0; t < 4; ++t) {
                AB bh, bl;
                bh.q = *(const uint4*)&bhS[t][lane][0];
                bl.q = *(const uint4*)&blS[t][lane][0];
                f32x4 cc = {b0v[t], b0v[t], b0v[t], b0v[t]};
                cc = mf(a0h, bh, cc); cc = mf(a0h, bl, cc); cc = mf(a0l, bh, cc);
                acc[mt][t] = cc;
            }
        }

#define STORE_RELU()                                                          \
        _Pragma("unroll")                                                     \
        for (int mt = 0; mt < 2; ++mt)                                        \
        _Pragma("unroll")                                                     \
        for (int t = 0; t < 4; ++t)                                           \
        _Pragma("unroll")                                                     \
        for (int r = 0; r < 4; ++r) {                                         \
            float vv = fmaxf(acc[mt][t][r], 0.0f);                            \
            const int row = mt * 16 + g * 4 + r;                              \
            const int col = (t * 16 + c16) ^ (r << 3);                        \
            hw[row * HSTRIDE + col] = vv;                                     \
        }

#define READ_A()                                                              \
        _Pragma("unroll")                                                     \
        for (int mt = 0; mt < 2; ++mt) {                                      \
            const int row = mt * 16 + c16;                                    \
            const int rb = row * HSTRIDE;                                     \
            const int rs = row & 3;                                           \
            _Pragma("unroll")                                                 \
            for (int ks = 0; ks < 2; ++ks) {                                  \
                const int cgs = (ks * 4 + g) ^ rs;                            \
                const float* p = hw + rb + cgs * 8;                           \
                float4 f0 = *(const float4*)p;                                \
                float4 f1 = *(const float4*)(p + 4);                          \
                float e[8] = {f0.x, f0.y, f0.z, f0.w, f1.x, f1.y, f1.z, f1.w};\
                split8(e, ah[mt][ks], al[mt][ks]);                            \
            }                                                                 \
        }

#define LAYER64(SET0, BV)                                                     \
        _Pragma("unroll")                                                     \
        for (int ks = 0; ks < 2; ++ks)                                        \
        _Pragma("unroll")                                                     \
        for (int t = 0; t < 4; ++t) {                                         \
            AB bh, bl;                                                        \
            bh.q = *(const uint4*)&bhS[(SET0) + ks * 4 + t][lane][0];         \
            bl.q = *(const uint4*)&blS[(SET0) + ks * 4 + t][lane][0];         \
            _Pragma("unroll")                                                 \
            for (int mt = 0; mt < 2; ++mt) {                                  \
                f32x4 cc = (ks == 0) ? f32x4{BV[t], BV[t], BV[t], BV[t]}      \
                                     : acc[mt][t];                            \
                cc = mf(ah[mt][ks], bh, cc);                                  \
                cc = mf(ah[mt][ks], bl, cc);                                  \
                cc = mf(al[mt][ks], bh, cc);                                  \
                acc[mt][t] = cc;                                              \
            }                                                                 \
        }

#define LFINAL(PASS)                                                          \
        _Pragma("unroll")                                                     \
        for (int mt = 0; mt < 2; ++mt) {                                      \
            f32x4 o = {bfv, bfv, bfv, bfv};                                   \
            _Pragma("unroll")                                                 \
            for (int ks = 0; ks < 2; ++ks) {                                  \
                AB bh, bl;                                                    \
                bh.q = *(const uint4*)&bhS[28 + ks][lane][0];                 \
                bl.q = *(const uint4*)&blS[28 + ks][lane][0];                 \
                o = mf(ah[mt][ks], bh, o);                                    \
                o = mf(ah[mt][ks], bl, o);                                    \
                o = mf(al[mt][ks], bh, o);                                    \
            }                                                                 \
            _Pragma("unroll")                                                 \
            for (int r = 0; r < 4; ++r) {                                     \
                const int s = ti * 32 + mt * 16 + g * 4 + r;                  \
                if (c16 < FOUT && s < n) {                                    \
                    const int b = list[s];                                    \
                    out[MO_OFF + b * 6 + (PASS) * 3 + c16] = o[r];            \
                }                                                             \
            }                                                                 \
        }

        STORE_RELU();     // H0
        READ_A();         // A = H0
        LAYER64(4, b1v);  // L1
        STORE_RELU();     // H1
        READ_A();         // A = H1
        LFINAL(0);        // output after layer 1
        LAYER64(12, b2v); // L2
        STORE_RELU();     // H2
        READ_A();         // A = H2
        LAYER64(20, b3v); // L3
        STORE_RELU();     // H3
        READ_A();         // A = H3
        LFINAL(1);        // final output
    }
}

extern "C" void kernel_launch(void* const* d_in, const int* in_sizes, int n_in,
                              void* d_out, int out_size, void* d_ws, size_t ws_size,
                              hipStream_t stream)
{
    const float* in = (const float*)d_in[0];
    const float* W0 = (const float*)d_in[1];
    const float* B0 = (const float*)d_in[2];
    const float* W1 = (const float*)d_in[3];
    const float* B1 = (const float*)d_in[4];
    const float* W2 = (const float*)d_in[5];
    const float* B2 = (const float*)d_in[6];
    const float* W3 = (const float*)d_in[7];
    const float* B3 = (const float*)d_in[8];
    const float* WF = (const float*)d_in[9];
    const float* BF = (const float*)d_in[10];
    float* out = (float*)d_out;

    unsigned char* wsb = (unsigned char*)d_ws;    // 65536 bytes

    k_index<<<BTOT / 256, 256, 0, stream>>>(in, out, wsb);
    k_mlp<<<dim3(NM, 4), 512, 0, stream>>>(in, W0, B0, W1, B1, W2, B2, W3, B3,
                                           WF, BF, (const uint4*)wsb, out);
}